// Round 1
// baseline (344.946 us; speedup 1.0000x reference)
//
#include <hip/hip_runtime.h>
#include <hip/hip_bf16.h>

typedef __attribute__((ext_vector_type(8))) short short8;
typedef __attribute__((ext_vector_type(4))) short short4_t;
typedef __attribute__((ext_vector_type(4))) float floatx4;

// ---------------- workspace layout (float offsets) ----------------
#define OFF_B1P   0        // conv1 B frags [7][64][8] bf16
#define OFF_B2P   1792     // conv2 B frags [2][14][64][8] bf16
#define OFF_B3P   8960     // conv3 B frags [4][27][64][8] bf16
#define OFF_WIHT  36608    // w_init_h^T  (64,256)
#define OFF_WIH1T 52992    // wih1^T      (64,256)
#define OFF_WI2T  69376    // w_init_h2^T (256,256)
#define OFF_WHH1B 134912   // whh1 bf16 row-major [t][k]
#define OFF_WIH2B 167680   // wih2 bf16 row-major
#define OFF_WHH2B 200448   // whh2 bf16 row-major
#define OFF_WL1P  233216   // w_lin1 MFMA frags [nt16][c162][lane64][j8] bf16
#define OFF_ME    896768   // mean_enc (512,64)
#define OFF_H     929536   // h0  (512,256)
#define OFF_H2    1060608  // h2_0(512,256)
#define OFF_IHC   1191680  // ih_const (512,256)
#define OFF_P1    1322752  // p1 bf16 [512][1296][16]
#define OFF_P2    6631168  // p2 bf16 [512][324][32]
#define OFF_P3BF  9285376  // p3 bf16 [512][5184]
#define OFF_T1    1322752  // lin1 partials 4x(512,256) fp32 (over dead p1)

#define S2_H 88
#define S2_D 1760
#define S3_H 88
#define S3_D 1760
#define S3_HALF 14080

static __device__ inline short f2bf(float f) {
  union { __hip_bfloat16 h; short s; } u;
  u.h = __float2bfloat16(f);
  return u.s;
}
static __device__ inline float bf2f(short s) {
  union { unsigned u; float f; } v;
  v.u = ((unsigned)(unsigned short)s) << 16;
  return v.f;
}
// 5-instr tanh: 1 - 2/(e^{2x}+1); inf-safe both directions
static __device__ inline float fast_tanh(float x) {
  float e = __expf(2.f * x);
  return __builtin_fmaf(-2.f, __builtin_amdgcn_rcpf(e + 1.f), 1.f);
}

// ---------------- prep: weight frag packs + RNN packs ----------------
__global__ __launch_bounds__(256) void prep_kernel(
    const float* __restrict__ w1, const float* __restrict__ w2, const float* __restrict__ w3,
    const float* __restrict__ w_init_h, const float* __restrict__ wih1,
    const float* __restrict__ w_init_h2, const float* __restrict__ whh1,
    const float* __restrict__ wih2, const float* __restrict__ whh2,
    float* __restrict__ ws) {
  int i = blockIdx.x * 256 + threadIdx.x;
  if (i < 3584) {
    int j = i & 7, l = (i >> 3) & 63, c = i >> 9;
    int k = c*32 + ((l >> 4) << 3) + j;
    int tap = k >> 3, icp = k & 7, oc = l & 15;
    float v = (tap < 27 && icp < 6) ? w1[(oc*6 + icp)*27 + tap] : 0.f;
    ((__hip_bfloat16*)(ws + OFF_B1P))[i] = __float2bfloat16(v);
    return;
  }
  i -= 3584;
  if (i < 14336) {
    int j = i & 7, l = (i >> 3) & 63, cc = i >> 9;
    int c = cc % 14, nt = cc / 14;
    int k = c*32 + ((l >> 4) << 3) + j;
    int tap = k >> 4, ic = k & 15, oc = nt*16 + (l & 15);
    float v = (tap < 27) ? w2[(oc*16 + ic)*27 + tap] : 0.f;
    ((__hip_bfloat16*)(ws + OFF_B2P))[i] = __float2bfloat16(v);
    return;
  }
  i -= 14336;
  if (i < 55296) {
    int j = i & 7, l = (i >> 3) & 63, cc = i >> 9;
    int c = cc % 27, nt = cc / 27;
    int k = c*32 + ((l >> 4) << 3) + j;
    int ic = k & 31, oc = nt*16 + (l & 15);
    ((__hip_bfloat16*)(ws + OFF_B3P))[i] = __float2bfloat16(w3[(oc*32 + ic)*27 + c]);
    return;
  }
  i -= 55296;
  if (i < 16384) { int t = i & 255, k = i >> 8; ws[OFF_WIHT + i]  = w_init_h[t*64 + k];  return; }
  i -= 16384;
  if (i < 16384) { int t = i & 255, k = i >> 8; ws[OFF_WIH1T + i] = wih1[t*64 + k];      return; }
  i -= 16384;
  if (i < 65536) { int t = i & 255, k = i >> 8; ws[OFF_WI2T + i]  = w_init_h2[t*256 + k]; return; }
  i -= 65536;
  if (i < 65536) { ((__hip_bfloat16*)(ws + OFF_WHH1B))[i] = __float2bfloat16(whh1[i]); return; }
  i -= 65536;
  if (i < 65536) { ((__hip_bfloat16*)(ws + OFF_WIH2B))[i] = __float2bfloat16(wih2[i]); return; }
  i -= 65536;
  if (i < 65536) { ((__hip_bfloat16*)(ws + OFF_WHH2B))[i] = __float2bfloat16(whh2[i]); return; }
}

// ---------------- conv1 MFMA + w_lin1 pack tail blocks ----------------
__global__ __launch_bounds__(256) void conv1_mfma(
    const float* __restrict__ x, const short* __restrict__ b1p,
    const float* __restrict__ bias, short* __restrict__ p1,
    const float* __restrict__ w_lin1, short* __restrict__ wl1p) {
  __shared__ __align__(16) short slab[8 * 74 * 5 * 8];
  int tid = threadIdx.x;
  if (blockIdx.x >= 2048) {
    int i = (blockIdx.x - 2048)*256 + tid;
    int j = i & 7, l = (i >> 3) & 63, cc = i >> 9;
    int c = cc % 162, nt = cc / 162;
    int k = c*32 + ((l >> 4) << 3) + j;
    int n = nt*16 + (l & 15);
    wl1p[i] = f2bf(w_lin1[n*5184 + k]);
    return;
  }
  int b = blockIdx.x >> 2, q = blockIdx.x & 3;
  for (int i = tid; i < 11840; i += 256) ((unsigned*)slab)[i] = 0u;
  __syncthreads();
  for (int i = tid; i < 2592; i += 256) {
    int dslot = i / 324;
    int r = i - dslot*324;
    int ic = r / 54;
    int f4 = r - ic*54;
    int d = 6*q - 1 + dslot;
    if ((unsigned)d < 24u) {
      float4 v = *(const float4*)(x + ((size_t)(b*6 + ic)*24 + d)*216 + f4*4);
      int pos = f4*4;
      int h0 = pos / 3, w0 = pos - h0*3;
      int hh = h0 + 1, ww = w0 + 1;
      float vv[4] = {v.x, v.y, v.z, v.w};
      #pragma unroll
      for (int e = 0; e < 4; ++e) {
        slab[((dslot*74 + hh)*5 + ww)*8 + ic] = f2bf(vv[e]);
        ++ww; if (ww == 4) { ww = 1; ++hh; }
      }
    }
  }
  int lane = tid & 63, wid = tid >> 6;
  int quad = lane >> 4, col = lane & 15;
  short8 bf[7];
  #pragma unroll
  for (int c = 0; c < 7; ++c) bf[c] = *(const short8*)(b1p + (c*64 + lane)*8);
  int tapoff[7];
  #pragma unroll
  for (int c = 0; c < 7; ++c) {
    int tap = c*4 + quad;
    int tt = tap < 27 ? tap : 26;
    int kd = tt/9, rr = tt - kd*9, kh = rr/3, kw = rr - kh*3;
    tapoff[c] = ((kd*74 + kh)*5 + kw)*8;
  }
  float bv = bias[col];
  __syncthreads();
  for (int tile = wid; tile < 81; tile += 4) {
    int m = tile*16 + col;
    int dd = m & 1, dh = (m >> 1) & 1;
    int P = m >> 2;
    int t2 = P/3; int w = P - t2*3;
    int pdl = t2/36; int ph = t2 - pdl*36;
    int base = (((2*pdl + dd)*74 + 2*ph + dh)*5 + w)*8;
    floatx4 acc = {0.f, 0.f, 0.f, 0.f};
    #pragma unroll
    for (int c = 0; c < 7; ++c) {
      short8 af = *(const short8*)(slab + base + tapoff[c]);
      acc = __builtin_amdgcn_mfma_f32_16x16x32_bf16(af, bf[c], acc, 0, 0, 0);
    }
    float v = fmaxf(fmaxf(acc[0], acc[1]), fmaxf(acc[2], acc[3]));
    v = fmaxf(v + bv, 0.f);
    int Pout = q*324 + tile*4 + quad;
    p1[((size_t)b*1296 + Pout)*16 + col] = f2bf(v);
  }
}

// ---------------- conv2 MFMA, halo slab: p1 -> p2 bf16 [b][324][32] ----------------
__global__ __launch_bounds__(256) void conv2_mfma(
    const short* __restrict__ p1, const short* __restrict__ b2p,
    const float* __restrict__ bias2, short* __restrict__ p2g) {
  __shared__ __align__(16) short slab[14 * S2_D];
  int tid = threadIdx.x;
  int b = blockIdx.x >> 1, qh = blockIdx.x & 1;
  short8 z8 = {0,0,0,0,0,0,0,0};
  for (int i = tid; i < 3080; i += 256) *(short8*)(slab + i*8) = z8;
  __syncthreads();
  for (int i = tid; i < 1440; i += 256) {
    int c8 = i % 6; int r = i / 6; int hr = r % 20; int d = r / 20;
    int hg = 18*qh - 1 + hr;
    if ((unsigned)hg < 36u) {
      short8 v = *(const short8*)(p1 + ((size_t)b*1296 + (d*36 + hg)*3)*16 + c8*8);
      *(short8*)(slab + (d+1)*S2_D + hr*S2_H + 16 + c8*8) = v;
    }
  }
  int lane = tid & 63, wid = tid >> 6;
  int quad = lane >> 4, col = lane & 15;
  short8 bf[2][14];
  #pragma unroll
  for (int nt = 0; nt < 2; ++nt)
    #pragma unroll
    for (int c = 0; c < 14; ++c)
      bf[nt][c] = *(const short8*)(b2p + ((nt*14 + c)*64 + lane)*8);
  int tq = quad >> 1, icoff = (quad & 1) * 8;
  int tapoff[14];
  #pragma unroll
  for (int c = 0; c < 14; ++c) {
    int tap = 2*c + tq; if (tap > 26) tap = 26;
    int kd = tap/9, rr = tap - kd*9, kh = rr/3, kw = rr - kh*3;
    tapoff[c] = kd*S2_D + kh*S2_H + kw*16 + icoff;
  }
  float bv0 = bias2[col], bv1 = bias2[16 + col];
  __syncthreads();
  for (int tile = wid; tile < 41; tile += 4) {
    int m = tile*16 + col; if (m > 647) m = 647;
    int dd = m & 1, dh = (m >> 1) & 1;
    int P = m >> 2;
    int t = P/3; int w = P - t*3;
    int pd = t/9; int phl = t - pd*9;
    int base = (2*pd + dd)*S2_D + (2*phl + dh)*S2_H + w*16;
    floatx4 a0 = {0.f,0.f,0.f,0.f}, a1 = {0.f,0.f,0.f,0.f};
    #pragma unroll
    for (int c = 0; c < 14; ++c) {
      short8 a = *(const short8*)(slab + base + tapoff[c]);
      a0 = __builtin_amdgcn_mfma_f32_16x16x32_bf16(a, bf[0][c], a0, 0, 0, 0);
      a1 = __builtin_amdgcn_mfma_f32_16x16x32_bf16(a, bf[1][c], a1, 0, 0, 0);
    }
    int P2l = tile*4 + quad;
    if (P2l < 162) {
      float v0 = fmaxf(fmaxf(fmaxf(a0[0],a0[1]), fmaxf(a0[2],a0[3])) + bv0, 0.f);
      float v1 = fmaxf(fmaxf(fmaxf(a1[0],a1[1]), fmaxf(a1[2],a1[3])) + bv1, 0.f);
      int t2 = P2l/3; int w2 = P2l - t2*3;
      int pd2 = t2/9; int ph2 = t2 - pd2*9;
      size_t off = ((size_t)b*324 + (pd2*18 + 9*qh + ph2)*3 + w2)*32;
      p2g[off + col] = f2bf(v0);
      p2g[off + 16 + col] = f2bf(v1);
    }
  }
}

// ---------------- conv3 MFMA, dual ic-half halo slabs: p2 -> p3bf + mean ----------------
__global__ __launch_bounds__(256) void conv3_mfma(
    const short* __restrict__ p2g, const short* __restrict__ b3p,
    const float* __restrict__ bias3,
    short* __restrict__ p3bf, float* __restrict__ me) {
  __shared__ __align__(16) short slab[2 * S3_HALF];
  __shared__ float smean[4][32];
  int tid = threadIdx.x;
  int b = blockIdx.x;
  short8 z8 = {0,0,0,0,0,0,0,0};
  for (int i = tid; i < 3520; i += 256) *(short8*)(slab + i*8) = z8;
  __syncthreads();
  for (int i = tid; i < 1296; i += 256) {
    int c8 = i & 1;
    int hv = (i >> 1) & 1;
    int cell = i >> 2;
    int t = cell/3; int w = cell - t*3;
    int d = t/18; int h = t - d*18;
    short8 v = *(const short8*)(p2g + ((size_t)b*324 + cell)*32 + hv*16 + c8*8);
    *(short8*)(slab + hv*S3_HALF + (d+1)*S3_D + (h+1)*S3_H + (w+1)*16 + c8*8) = v;
  }
  int lane = tid & 63, wid = tid >> 6;
  int quad = lane >> 4, col = lane & 15;
  int ntp = (wid & 1) * 2;
  int tsel = wid >> 1;
  short8 bf[2][27];
  #pragma unroll
  for (int u = 0; u < 2; ++u)
    #pragma unroll
    for (int c = 0; c < 27; ++c)
      bf[u][c] = *(const short8*)(b3p + (((ntp+u)*27 + c)*64 + lane)*8);
  const short* sb = slab + (quad >> 1)*S3_HALF + (quad & 1)*8;
  float bva = bias3[ntp*16 + col], bvb = bias3[(ntp+1)*16 + col];
  float ms0 = 0.f, ms1 = 0.f;
  __syncthreads();
  for (int tile = tsel; tile < 21; tile += 2) {
    int m = tile*16 + col; if (m > 323) m = 323;
    int dd = m & 1, dh = (m >> 1) & 1;
    int P = m >> 2;
    int t = P/3; int w = P - t*3;
    int pd = t/9; int ph = t - pd*9;
    const short* ap = sb + (2*pd + dd)*S3_D + (2*ph + dh)*S3_H + w*16;
    floatx4 a0 = {0.f,0.f,0.f,0.f}, a1 = {0.f,0.f,0.f,0.f};
    #pragma unroll
    for (int c = 0; c < 27; ++c) {
      const int kd = c/9, rr = c - kd*9, kh = rr/3, kw = rr - kh*3;
      short8 a = *(const short8*)(ap + kd*S3_D + kh*S3_H + kw*16);
      a0 = __builtin_amdgcn_mfma_f32_16x16x32_bf16(a, bf[0][c], a0, 0, 0, 0);
      a1 = __builtin_amdgcn_mfma_f32_16x16x32_bf16(a, bf[1][c], a1, 0, 0, 0);
    }
    int Pout = tile*4 + quad;
    if (Pout < 81) {
      float v0 = fmaxf(fmaxf(fmaxf(a0[0],a0[1]), fmaxf(a0[2],a0[3])) + bva, 0.f);
      float v1 = fmaxf(fmaxf(fmaxf(a1[0],a1[1]), fmaxf(a1[2],a1[3])) + bvb, 0.f);
      size_t oi = ((size_t)b*81 + Pout)*64 + ntp*16 + col;
      p3bf[oi] = f2bf(v0);
      p3bf[oi + 16] = f2bf(v1);
      ms0 += v0; ms1 += v1;
    }
  }
  ms0 += __shfl_xor(ms0, 16, 64); ms0 += __shfl_xor(ms0, 32, 64);
  ms1 += __shfl_xor(ms1, 16, 64); ms1 += __shfl_xor(ms1, 32, 64);
  if (lane < 16) { smean[wid][lane] = ms0; smean[wid][16 + lane] = ms1; }
  __syncthreads();
  if (tid < 64) {
    float s = (tid < 32) ? (smean[0][tid] + smean[2][tid])
                         : (smean[1][tid-32] + smean[3][tid-32]);
    me[b*64 + tid] = s * (1.f / 81.f);
  }
}

// ---------------- initial projections: 64 blocks x 8 rows ----------------
__global__ __launch_bounds__(256) void init_kernel(
    const float* __restrict__ me, const float* __restrict__ wiht,
    const float* __restrict__ b_init_h, const float* __restrict__ wih1t,
    const float* __restrict__ bih1, const float* __restrict__ bhh1,
    const float* __restrict__ wi2t, const float* __restrict__ b_init_h2,
    float* __restrict__ hout, float* __restrict__ h2out, float* __restrict__ ihcout) {
  __shared__ float sme[8][64];
  __shared__ float shl[8][256];
  int t = threadIdx.x; int bb = blockIdx.x * 8;
  for (int i = t; i < 512; i += 256) {
    int m = i >> 6, c = i & 63;
    sme[m][c] = me[(bb + m)*64 + c];
  }
  __syncthreads();
  float a[8], cc[8];
  float ba = b_init_h[t], bc = bih1[t] + bhh1[t];
  #pragma unroll
  for (int r = 0; r < 8; ++r) { a[r] = ba; cc[r] = bc; }
  #pragma unroll 2
  for (int k = 0; k < 64; ++k) {
    float w1v = wiht[k*256 + t], w2v = wih1t[k*256 + t];
    #pragma unroll
    for (int r = 0; r < 8; ++r) {
      float m = sme[r][k];
      a[r]  += m * w1v;
      cc[r] += m * w2v;
    }
  }
  #pragma unroll
  for (int r = 0; r < 8; ++r) {
    hout[(size_t)(bb + r)*256 + t] = a[r];
    ihcout[(size_t)(bb + r)*256 + t] = cc[r];
    shl[r][t] = a[r];
  }
  __syncthreads();
  float a2[8];
  float b2 = b_init_h2[t];
  #pragma unroll
  for (int r = 0; r < 8; ++r) a2[r] = b2;
  #pragma unroll 2
  for (int k = 0; k < 256; ++k) {
    float wv = wi2t[k*256 + t];
    #pragma unroll
    for (int r = 0; r < 8; ++r) a2[r] += shl[r][k] * wv;
  }
  #pragma unroll
  for (int r = 0; r < 8; ++r) h2out[(size_t)(bb + r)*256 + t] = a2[r];
}

// ---------------- fused tail: blocks 0-31 RNN (single-barrier pipelined),
//                  blocks 32-95 lin1 split-K GEMM ----------
// RNN rewrite vs prior version: the three weight operand sets (whh1/wih2/whh2,
// 192 VGPRs) MUST be register-resident across all 24 steps. The prior build
// compiled to VGPR_Count=128 (4 waves/EU target) -> weights were spilled or
// re-fetched every step (~384 KB/block/step of L2 traffic; 5700 cyc/step).
// Fix: __launch_bounds__(512, 2) -> 256-VGPR budget (1 block/CU, 2 waves/SIMD),
// and a single fused c-loop so hb/gb are 8 transient regs instead of a 32-reg
// array. b2 / w_fc constants packed to bf16 (-8 VGPR; exact here, biases are 0).
// Live set: 192 weights + 24 acc + 8 transient + ~26 consts/addr ~= 250 <= 256.
__global__ __launch_bounds__(512, 2) void tail_kernel(
    const float* __restrict__ hin, const float* __restrict__ h2in,
    const float* __restrict__ ihc,
    const short* __restrict__ whh1b, const short* __restrict__ wih2b,
    const short* __restrict__ whh2b,
    const float* __restrict__ bih2, const float* __restrict__ bhh2,
    const float* __restrict__ w_fc, const float* __restrict__ b_fc,
    float* __restrict__ preds,
    const short* __restrict__ p3bf, const short* __restrict__ wl1p,
    const float* __restrict__ b_lin1, float* __restrict__ t1) {
  __shared__ __align__(16) short hbuf[2][16][264];   // [m][k] bf16
  __shared__ __align__(16) short h2buf[2][16][264];
  __shared__ float predsAll[23][8][16];
  int tid = threadIdx.x;

  if (blockIdx.x >= 32) {
    // ---- lin arm: split-K x4 GEMM (512x5184)x(5184x256); 2 sub-tiles/block ----
    int sub = tid >> 8, stid = tid & 255;
    int lane = stid & 63, w4 = stid >> 6;
    int quad = lane >> 4, col = lane & 15;
    int idx = (blockIdx.x - 32)*2 + sub;   // [0,128)
    int mt = idx & 7, ntb = (idx >> 3) & 3, kz = idx >> 5;
    int c0 = kz*41; if (kz == 3) c0 = 122;
    int c1 = c0 + ((kz >= 2) ? 40 : 41);
    int m0 = mt*64 + w4*16;
    floatx4 acc[4];
    #pragma unroll
    for (int t = 0; t < 4; ++t) {
      float bv = (kz == 0) ? b_lin1[ntb*64 + t*16 + col] : 0.f;
      #pragma unroll
      for (int r = 0; r < 4; ++r) acc[t][r] = bv;
    }
    const short* arow = p3bf + (size_t)(m0 + col)*5184 + quad*8;
    const short* bbase = wl1p + ((size_t)(ntb*4)*162)*512 + lane*8;
    #pragma unroll 2
    for (int c = c0; c < c1; ++c) {
      short8 a = *(const short8*)(arow + c*32);
      #pragma unroll
      for (int t = 0; t < 4; ++t) {
        short8 b = *(const short8*)(bbase + (size_t)(t*162 + c)*512);
        acc[t] = __builtin_amdgcn_mfma_f32_16x16x32_bf16(a, b, acc[t], 0, 0, 0);
      }
    }
    float* to = t1 + (size_t)kz * 131072;
    #pragma unroll
    for (int t = 0; t < 4; ++t)
      #pragma unroll
      for (int r = 0; r < 4; ++r)
        to[(size_t)(m0 + quad*4 + r)*256 + ntb*64 + t*16 + col] = acc[t][r];
    return;
  }

  // ---- RNN arm: 8 waves, each owns n-slice [w*32, w*32+32) of ALL matrices ----
  int lane = tid & 63, wid = tid >> 6;
  int quad = lane >> 4, col = lane & 15;
  int bb = blockIdx.x * 16;
  int n0 = wid * 32;
  short8 w1f[2][8], w2f[2][8], w3f[2][8];
  #pragma unroll
  for (int t = 0; t < 2; ++t)
    #pragma unroll
    for (int c = 0; c < 8; ++c) {
      int off = (n0 + t*16 + col)*256 + c*32 + quad*8;
      w1f[t][c] = *(const short8*)(whh1b + off);   // whh1: A-operand
      w2f[t][c] = *(const short8*)(wih2b + off);   // wih2
      w3f[t][c] = *(const short8*)(whh2b + off);   // whh2
    }
  // fp32 ihc (accuracy: nonzero, feeds h every step); bf16-packed b2 / w_fc
  // (biases are zero in this problem -> exact; w_fc bf16 err ~0.4% on preds).
  float4 ihcr[2];
  short8 b2p, wfp;
  #pragma unroll
  for (int t = 0; t < 2; ++t) {
    int n = n0 + t*16 + quad*4;
    ihcr[t] = *(const float4*)(ihc + (size_t)(bb + col)*256 + n);
    #pragma unroll
    for (int r = 0; r < 4; ++r) {
      b2p[t*4 + r] = f2bf(bih2[n + r] + bhh2[n + r]);
      wfp[t*4 + r] = f2bf(w_fc[n + r]);
    }
  }
  float bfc = b_fc[0];

  for (int i = tid; i < 4096; i += 512) {
    int m = i >> 8, k = i & 255;
    hbuf[0][m][k]  = f2bf(hin[(size_t)(bb + m)*256 + k]);
    h2buf[0][m][k] = f2bf(h2in[(size_t)(bb + m)*256 + k]);
    h2buf[1][m][k] = 0;   // z-MFMAs at i=0 read this (result discarded)
  }
  __syncthreads();

  #pragma unroll 1
  for (int i = 0; i < 24; ++i) {
    int cur = i & 1;
    floatx4 a1[2], y0, y1, z0, z1;
    #pragma unroll
    for (int t = 0; t < 2; ++t) {
      a1[t][0] = ihcr[t].x; a1[t][1] = ihcr[t].y;
      a1[t][2] = ihcr[t].z; a1[t][3] = ihcr[t].w;
    }
    #pragma unroll
    for (int r = 0; r < 4; ++r) { y0[r] = 0.f; y1[r] = 0.f; z0[r] = 0.f; z1[r] = 0.f; }
    // fused c-loop: one hb read feeds 4 MFMA (a1[0],a1[1],y0,y1); gb feeds 2.
    #pragma unroll
    for (int c = 0; c < 8; ++c) {
      short8 hb = *(const short8*)&hbuf[cur][col][c*32 + quad*8];
      short8 gb = *(const short8*)&h2buf[cur ^ 1][col][c*32 + quad*8];
      a1[0] = __builtin_amdgcn_mfma_f32_16x16x32_bf16(w1f[0][c], hb, a1[0], 0, 0, 0);
      a1[1] = __builtin_amdgcn_mfma_f32_16x16x32_bf16(w1f[1][c], hb, a1[1], 0, 0, 0);
      y0    = __builtin_amdgcn_mfma_f32_16x16x32_bf16(w2f[0][c], hb, y0, 0, 0, 0);
      y1    = __builtin_amdgcn_mfma_f32_16x16x32_bf16(w2f[1][c], hb, y1, 0, 0, 0);
      z0    = __builtin_amdgcn_mfma_f32_16x16x32_bf16(w3f[0][c], gb, z0, 0, 0, 0);
      z1    = __builtin_amdgcn_mfma_f32_16x16x32_bf16(w3f[1][c], gb, z1, 0, 0, 0);
    }
    if (i < 23) {
      // h_{i+1} = tanh(ihc + whh1 @ h_i^T)
      #pragma unroll
      for (int t = 0; t < 2; ++t) {
        short4_t pk;
        #pragma unroll
        for (int r = 0; r < 4; ++r) pk[r] = f2bf(fast_tanh(a1[t][r]));
        *(short4_t*)&hbuf[cur ^ 1][col][n0 + t*16 + quad*4] = pk;
      }
    }
    if (i > 0) {
      // h2_i = tanh(wih2 @ h_i^T + whh2 @ h2_{i-1}^T + b2); pred_{i-1}
      float pr = 0.f;
      short4_t o0, o1;
      #pragma unroll
      for (int r = 0; r < 4; ++r) {
        float t0 = fast_tanh(y0[r] + z0[r] + bf2f(b2p[r]));
        float t1 = fast_tanh(y1[r] + z1[r] + bf2f(b2p[4 + r]));
        o0[r] = f2bf(t0); o1[r] = f2bf(t1);
        pr += t0*bf2f(wfp[r]) + t1*bf2f(wfp[4 + r]);
      }
      *(short4_t*)&h2buf[cur][col][n0 + quad*4] = o0;
      *(short4_t*)&h2buf[cur][col][n0 + 16 + quad*4] = o1;
      pr += __shfl_xor(pr, 16, 64);
      pr += __shfl_xor(pr, 32, 64);
      if (lane < 16) predsAll[i - 1][wid][lane] = pr;
    }
    __syncthreads();
  }
  if (tid < 16) {
    #pragma unroll 1
    for (int p = 0; p < 23; ++p) {
      float sv = bfc;
      #pragma unroll
      for (int w = 0; w < 8; ++w) sv += predsAll[p][w][tid];
      preds[(size_t)(bb + tid)*23 + p] = sv;
    }
  }
}

// ---------------- lin epilogue: sum partials + tanh + (256 -> 12) ----------------
__global__ __launch_bounds__(256) void lin_fin(
    const float* __restrict__ t1, const float* __restrict__ w_lin2,
    const float* __restrict__ b_lin2, float* __restrict__ outc) {
  __shared__ float st[16][257];
  int tid = threadIdx.x;
  int bb = blockIdx.x * 16;
  for (int i = tid; i < 4096; i += 256) {
    int m = i >> 8, k = i & 255;
    size_t i0 = (size_t)(bb + m)*256 + k;
    float s = t1[i0] + t1[i0 + 131072] + t1[i0 + 262144] + t1[i0 + 393216];
    st[m][k] = fast_tanh(s);
  }
  __syncthreads();
  if (tid < 192) {
    int r = tid / 12, j = tid % 12;
    float s = b_lin2[j];
    #pragma unroll 1
    for (int k = 0; k < 256; ++k) s += st[r][k] * w_lin2[j*256 + k];
    outc[(size_t)(bb + r)*12 + j] = s;
  }
}

// ---------------- launch ----------------
extern "C" void kernel_launch(void* const* d_in, const int* in_sizes, int n_in,
                              void* d_out, int out_size, void* d_ws, size_t ws_size,
                              hipStream_t stream) {
  const float* x         = (const float*)d_in[0];
  const float* w1        = (const float*)d_in[1];
  const float* b1        = (const float*)d_in[2];
  const float* w2        = (const float*)d_in[3];
  const float* b2        = (const float*)d_in[4];
  const float* w3        = (const float*)d_in[5];
  const float* b3        = (const float*)d_in[6];
  const float* wih1      = (const float*)d_in[7];
  const float* whh1      = (const float*)d_in[8];
  const float* bih1      = (const float*)d_in[9];
  const float* bhh1      = (const float*)d_in[10];
  const float* wih2      = (const float*)d_in[11];
  const float* whh2      = (const float*)d_in[12];
  const float* bih2      = (const float*)d_in[13];
  const float* bhh2      = (const float*)d_in[14];
  const float* w_init_h  = (const float*)d_in[15];
  const float* b_init_h  = (const float*)d_in[16];
  const float* w_init_h2 = (const float*)d_in[17];
  const float* b_init_h2 = (const float*)d_in[18];
  const float* w_fc      = (const float*)d_in[19];
  const float* b_fc      = (const float*)d_in[20];
  const float* w_lin1    = (const float*)d_in[21];
  const float* b_lin1    = (const float*)d_in[22];
  const float* w_lin2    = (const float*)d_in[23];
  const float* b_lin2    = (const float*)d_in[24];
  float* ws  = (float*)d_ws;
  float* out = (float*)d_out;

  prep_kernel<<<1438, 256, 0, stream>>>(w1, w2, w3, w_init_h, wih1, w_init_h2,
                                        whh1, wih2, whh2, ws);
  conv1_mfma<<<7232, 256, 0, stream>>>(x, (const short*)(ws + OFF_B1P), b1,
                                       (short*)(ws + OFF_P1),
                                       w_lin1, (short*)(ws + OFF_WL1P));
  conv2_mfma<<<1024, 256, 0, stream>>>((const short*)(ws + OFF_P1),
                                       (const short*)(ws + OFF_B2P), b2,
                                       (short*)(ws + OFF_P2));
  conv3_mfma<<<512, 256, 0, stream>>>((const short*)(ws + OFF_P2),
                                      (const short*)(ws + OFF_B3P), b3,
                                      (short*)(ws + OFF_P3BF), ws + OFF_ME);
  init_kernel<<<64, 256, 0, stream>>>(ws + OFF_ME, ws + OFF_WIHT, b_init_h, ws + OFF_WIH1T,
                                      bih1, bhh1, ws + OFF_WI2T, b_init_h2,
                                      ws + OFF_H, ws + OFF_H2, ws + OFF_IHC);
  tail_kernel<<<96, 512, 0, stream>>>(ws + OFF_H, ws + OFF_H2, ws + OFF_IHC,
                                      (const short*)(ws + OFF_WHH1B),
                                      (const short*)(ws + OFF_WIH2B),
                                      (const short*)(ws + OFF_WHH2B),
                                      bih2, bhh2, w_fc, b_fc, out,
                                      (const short*)(ws + OFF_P3BF),
                                      (const short*)(ws + OFF_WL1P),
                                      b_lin1, ws + OFF_T1);
  lin_fin<<<32, 256, 0, stream>>>(ws + OFF_T1, w_lin2, b_lin2, out + 11776);
}